// Round 8
// baseline (1022.618 us; speedup 1.0000x reference)
//
#include <hip/hip_runtime.h>
#include <hip/hip_bf16.h>

#define BB 4
#define NN 2048
#define DD 128
#define HH 4
#define LOG2E 1.4426950408889634f

typedef __attribute__((ext_vector_type(8))) short bf16x8;   // 8 bf16 in 4 VGPRs
typedef __attribute__((ext_vector_type(4))) float f32x4;    // native 4xfloat

__device__ __forceinline__ unsigned short f2bf(float f) {
    union { float f; unsigned int u; } v; v.f = f;
    unsigned int r = v.u + 0x7FFF + ((v.u >> 16) & 1);      // round-nearest-even
    return (unsigned short)(r >> 16);
}

// ---------------------------------------------------------------------------
// Kernel A: wsv[h][i] = sum_o W[h,i,o]*a[h,o]; wdv likewise with a[h,D+o].
// ---------------------------------------------------------------------------
__global__ __launch_bounds__(128) void k_wvec(const float* __restrict__ W,
                                              const float* __restrict__ a,
                                              float* __restrict__ wsv,
                                              float* __restrict__ wdv) {
    int h = blockIdx.x;
    int i = threadIdx.x;
    const float* Wr  = W + (h * DD + i) * DD;
    const float* as_ = a + h * 2 * DD;
    const float* ad_ = as_ + DD;
    float s = 0.f, d = 0.f;
    for (int o = 0; o < DD; ++o) {
        float w = Wr[o];
        s += w * as_[o];
        d += w * ad_[o];
    }
    wsv[h * DD + i] = s;
    wdv[h * DD + i] = d;
}

// ---------------------------------------------------------------------------
// Kernel B: s[b,h,n] = x[b,n,:] . wsv[h]; d likewise. 64 rows/block.
// ---------------------------------------------------------------------------
__global__ __launch_bounds__(256) void k_sd(const float* __restrict__ x,
                                            const float* __restrict__ wsv,
                                            const float* __restrict__ wdv,
                                            float* __restrict__ s_out,
                                            float* __restrict__ d_out_) {
    __shared__ float xs[64 * 129];
    __shared__ float ws[4 * 129], wd[4 * 129];
    int tid = threadIdx.x;
    int b  = blockIdx.x / (NN / 64);
    int nb = (blockIdx.x % (NN / 64)) * 64;
    for (int idx = tid; idx < HH * DD; idx += 256) {
        ws[(idx >> 7) * 129 + (idx & 127)] = wsv[idx];
        wd[(idx >> 7) * 129 + (idx & 127)] = wdv[idx];
    }
    for (int idx = tid; idx < 64 * 128; idx += 256) {
        int r = idx >> 7, c = idx & 127;
        xs[r * 129 + c] = x[((size_t)b * NN + nb + r) * DD + c];
    }
    __syncthreads();
    int h = tid & 3, r = tid >> 2;
    float sv = 0.f, dv = 0.f;
#pragma unroll 8
    for (int i = 0; i < DD; ++i) {
        float xv = xs[r * 129 + i];
        sv += xv * ws[h * 129 + i];
        dv += xv * wd[h * 129 + i];
    }
    int n = nb + r;
    s_out[(b * HH + h) * NN + n] = sv;
    d_out_[(b * HH + h) * NN + n] = dv;
}

// ---------------------------------------------------------------------------
// Kernel H: h[b,h,n,o] = sum_i x[b,n,i]*W[h,i,o]; stored TRANSPOSED as bf16:
// hT[bh][o][n] (n contiguous) — MFMA B-operand layout for k_attn_fused.
// ---------------------------------------------------------------------------
__global__ __launch_bounds__(256) void k_h(const float* __restrict__ x,
                                           const float* __restrict__ W,
                                           unsigned short* __restrict__ hT) {
    __shared__ float xs[32 * 129];
    int tid = threadIdx.x;
    int bh = blockIdx.x / (NN / 32);
    int nb = (blockIdx.x % (NN / 32)) * 32;
    int b = bh >> 2, h = bh & 3;
    for (int idx = tid; idx < 32 * 128; idx += 256) {
        int r = idx >> 7, c = idx & 127;
        xs[r * 129 + c] = x[((size_t)b * NN + nb + r) * DD + c];
    }
    __syncthreads();
    int o = tid & 127, rh = tid >> 7;
    float acc[16];
#pragma unroll
    for (int j = 0; j < 16; ++j) acc[j] = 0.f;
    for (int i = 0; i < DD; ++i) {
        float wv = W[(h * DD + i) * DD + o];
#pragma unroll
        for (int j = 0; j < 16; ++j) acc[j] += xs[(rh * 16 + j) * 129 + i] * wv;
    }
    bf16x8 p0, p1;
#pragma unroll
    for (int j = 0; j < 8; ++j) { p0[j] = (short)f2bf(acc[j]); p1[j] = (short)f2bf(acc[8 + j]); }
    unsigned short* dst = hT + ((size_t)bh * DD + o) * NN + nb + rh * 16;
    *(bf16x8*)dst = p0;
    *(bf16x8*)(dst + 8) = p1;
}

// ---------------------------------------------------------------------------
// Kernel 3 (FUSED): per (b,h,64-n-tile):
//   pass 1: L[row] = sum_m mask*exp(lrelu(s+d))  (no max-subtract: |v|<~8,
//           exp in [3e-4,3e3], fp32-safe; M cancels in alpha exactly)
//   pass 2: per 128-m stage: alpha fp32 -> global (output!), alpha bf16 ->
//           LDS A-tile, hT chunk -> LDS B-tile, 4 waves x 8 o-tiles MFMA.
// Replaces k_stats + k_attn_mfma + k_alpha; adj read once (pass-2 L2-hot).
// ---------------------------------------------------------------------------
__global__ __launch_bounds__(256, 2) void k_attn_fused(
        const int* __restrict__ adj,
        const float* __restrict__ s_in,
        const float* __restrict__ d_in_,
        const unsigned short* __restrict__ hT,
        float* __restrict__ alpha_out,
        float* __restrict__ out_scr) {
    __shared__ unsigned short al_lds[64 * 136];    // alpha tile (bf16), +8 pad
    __shared__ unsigned short hT_lds[128 * 136];   // h chunk (o-major), +8 pad
    __shared__ float dall[NN];
    __shared__ float srow[64], Lirow[64];
    __shared__ float red[256];
    int tid = threadIdx.x;
    int bh = blockIdx.x >> 5;
    int nb = (blockIdx.x & 31) * 64;
    int b = bh >> 2;

    if (tid < 64) srow[tid] = s_in[bh * NN + nb + tid];
    for (int i = tid; i < NN / 4; i += 256)
        ((float4*)dall)[i] = ((const float4*)(d_in_ + (size_t)bh * NN))[i];
    __syncthreads();

    int an = tid >> 2;                    // row (0..63), 4 threads per row
    int mq = (tid & 3) * 512;             // pass-1 m-segment
    int mseg = (tid & 3) * 32;            // pass-2 m-segment
    float sn = srow[an];
    const int* arow = adj + ((size_t)b * NN + nb + an) * NN;

    // ---- pass 1: row sum of exp ----
    float Lp = 0.f;
    for (int mm = 0; mm < 512; mm += 8) {
        int4 a0 = *(const int4*)(arow + mq + mm);
        int4 a1 = *(const int4*)(arow + mq + mm + 4);
        float4 d0 = *(const float4*)&dall[mq + mm];
        float4 d1 = *(const float4*)&dall[mq + mm + 4];
        int   av[8] = {a0.x, a0.y, a0.z, a0.w, a1.x, a1.y, a1.z, a1.w};
        float dv[8] = {d0.x, d0.y, d0.z, d0.w, d1.x, d1.y, d1.z, d1.w};
#pragma unroll
        for (int j = 0; j < 8; ++j) {
            float t = sn + dv[j];
            float v = t > 0.f ? t : 0.2f * t;
            Lp += (av[j] != 0) ? exp2f(v * LOG2E) : 0.f;
        }
    }
    red[tid] = Lp;
    __syncthreads();
    if (tid < 64) {
        float L = red[4 * tid] + red[4 * tid + 1] + red[4 * tid + 2] + red[4 * tid + 3];
        Lirow[tid] = (L > 0.f) ? 1.f / L : 0.f;
    }
    __syncthreads();
    float Lin = Lirow[an];

    // pass-2 mappings
    int ho = tid >> 1, hhalf = (tid & 1) * 64;
    const unsigned short* hrow = hT + ((size_t)bh * DD + ho) * NN;
    int l = tid & 63, w = tid >> 6, col = l & 15, quad = l >> 4;
    float* arow_out = alpha_out + ((size_t)bh * NN + nb + an) * NN;

    f32x4 acc[8];
#pragma unroll
    for (int ot = 0; ot < 8; ++ot) acc[ot] = (f32x4){0.f, 0.f, 0.f, 0.f};

    for (int mb = 0; mb < NN; mb += 128) {
        __syncthreads();   // prev-stage MFMA reads complete before overwrite
        // --- phase A: alpha -> fp32 global (nontemporal) + bf16 LDS ---
        const int4* ap = (const int4*)(arow + mb + mseg);
#pragma unroll
        for (int g = 0; g < 4; ++g) {
            int4 a0 = ap[2 * g], a1 = ap[2 * g + 1];
            float4 d0 = *(const float4*)&dall[mb + mseg + g * 8];
            float4 d1 = *(const float4*)&dall[mb + mseg + g * 8 + 4];
            int   av[8] = {a0.x, a0.y, a0.z, a0.w, a1.x, a1.y, a1.z, a1.w};
            float dv[8] = {d0.x, d0.y, d0.z, d0.w, d1.x, d1.y, d1.z, d1.w};
            float ev[8];
            bf16x8 pk;
#pragma unroll
            for (int j = 0; j < 8; ++j) {
                float t = sn + dv[j];
                float v = t > 0.f ? t : 0.2f * t;
                float e = (av[j] != 0) ? exp2f(v * LOG2E) * Lin : 0.f;
                ev[j] = e;
                pk[j] = (short)f2bf(e);
            }
            *(bf16x8*)&al_lds[an * 136 + mseg + g * 8] = pk;
            f32x4 e0 = {ev[0], ev[1], ev[2], ev[3]};
            f32x4 e1 = {ev[4], ev[5], ev[6], ev[7]};
            f32x4* dst = (f32x4*)(arow_out + mb + mseg + g * 8);
            __builtin_nontemporal_store(e0, dst);        // write-once stream
            __builtin_nontemporal_store(e1, dst + 1);
        }
        // --- phase B: stage hT chunk [128 o][128 m] ---
#pragma unroll
        for (int q = 0; q < 8; ++q) {
            bf16x8 hv = *(const bf16x8*)(hrow + mb + hhalf + q * 8);
            *(bf16x8*)&hT_lds[ho * 136 + hhalf + q * 8] = hv;
        }
        __syncthreads();
        // --- phase C: MFMA ---
#pragma unroll
        for (int k = 0; k < 4; ++k) {
            bf16x8 af = *(const bf16x8*)&al_lds[(w * 16 + col) * 136 + k * 32 + quad * 8];
#pragma unroll
            for (int ot = 0; ot < 8; ++ot) {
                bf16x8 bfv = *(const bf16x8*)&hT_lds[(ot * 16 + col) * 136 + k * 32 + quad * 8];
                acc[ot] = __builtin_amdgcn_mfma_f32_16x16x32_bf16(af, bfv, acc[ot], 0, 0, 0);
            }
        }
    }
    // epilogue: C/D layout col=lane&15, row=quad*4+reg
#pragma unroll
    for (int ot = 0; ot < 8; ++ot)
#pragma unroll
        for (int r = 0; r < 4; ++r)
            out_scr[((size_t)bh * NN + nb + w * 16 + quad * 4 + r) * DD + ot * 16 + col] =
                acc[ot][r];
}

// ---------------------------------------------------------------------------
// Kernel 4: output[b,n,o] = concat_h(out_scr) @ Wp + bias, fp32 store.
// ---------------------------------------------------------------------------
__global__ __launch_bounds__(256) void k_proj(const float* __restrict__ out_scr,
                                              const float* __restrict__ Wp,
                                              const float* __restrict__ bias,
                                              float* __restrict__ out) {
    __shared__ float cs[16 * 512];
    int tid = threadIdx.x;
    int b  = blockIdx.x / (NN / 16);
    int nb = (blockIdx.x % (NN / 16)) * 16;
    for (int idx = tid; idx < 16 * 512; idx += 256) {
        int r = idx >> 9, c = idx & 511;
        int hh = c >> 7, oo = c & 127;
        cs[idx] = out_scr[((size_t)(b * HH + hh) * NN + nb + r) * DD + oo];
    }
    __syncthreads();
    int o = tid & 127, rg = tid >> 7;
    float bv = bias[o];
    float acc[8];
#pragma unroll
    for (int j = 0; j < 8; ++j) acc[j] = bv;
    for (int k = 0; k < 512; ++k) {
        float w = Wp[k * DD + o];
#pragma unroll
        for (int j = 0; j < 8; ++j) acc[j] += cs[(rg * 8 + j) * 512 + k] * w;
    }
#pragma unroll
    for (int j = 0; j < 8; ++j)
        out[((size_t)b * NN + nb + rg * 8 + j) * DD + o] = acc[j];
}

// ---------------------------------------------------------------------------
extern "C" void kernel_launch(void* const* d_in, const int* in_sizes, int n_in,
                              void* d_out, int out_size, void* d_ws, size_t ws_size,
                              hipStream_t stream) {
    const float* x    = (const float*)d_in[0];
    const int*   adj  = (const int*)d_in[1];
    const float* W    = (const float*)d_in[2];
    const float* a    = (const float*)d_in[3];
    const float* Wp   = (const float*)d_in[4];
    const float* bias = (const float*)d_in[5];

    float* out       = (float*)d_out;
    float* alpha_out = out + (size_t)BB * NN * DD;   // fp32 [B,H,N,N], written by k_attn_fused

    // All scratch in d_ws (~34 MB used):
    //   hT      bf16 [B*H][D][N]  = B*H*N*D ushorts = B*H*N*D/2 floats (16.8 MB)
    //   out_scr fp32 [B*H][N][D]  (16.8 MB)
    //   + small stat vectors
    float* ws          = (float*)d_ws;
    unsigned short* hT = (unsigned short*)ws;
    float* out_scr = ws + (size_t)BB * HH * NN * DD / 2;
    float* wsv = out_scr + (size_t)BB * HH * NN * DD;          // 512 f
    float* wdv = wsv + HH * DD;                                // 512 f
    float* s_  = wdv + HH * DD;                                // 32768 f
    float* d_  = s_ + BB * HH * NN;                            // 32768 f

    k_wvec<<<HH, 128, 0, stream>>>(W, a, wsv, wdv);
    k_sd<<<BB * NN / 64, 256, 0, stream>>>(x, wsv, wdv, s_, d_);
    k_h<<<BB * HH * (NN / 32), 256, 0, stream>>>(x, W, hT);
    k_attn_fused<<<BB * HH * (NN / 64), 256, 0, stream>>>(adj, s_, d_, hT,
                                                          alpha_out, out_scr);
    k_proj<<<BB * (NN / 16), 256, 0, stream>>>(out_scr, Wp, bias, out);
}